// Round 9
// baseline (414.832 us; speedup 1.0000x reference)
//
#include <hip/hip_runtime.h>
#include <hip/hip_bf16.h>

typedef __attribute__((ext_vector_type(8))) short bf16x8;
typedef __attribute__((ext_vector_type(4))) float f32x4;

__device__ __forceinline__ short f2bf(float f) {
    union { float f; unsigned u; } v; v.f = f;
    unsigned r = v.u + 0x7fffu + ((v.u >> 16) & 1u);
    return (short)(r >> 16);
}

__device__ __forceinline__ void gl2lds16(const void* g, void* l) {
    __builtin_amdgcn_global_load_lds(
        (const __attribute__((address_space(1))) unsigned int*)g,
        (__attribute__((address_space(3))) unsigned int*)l,
        16, 0, 0);
}

#define KP  800               // K padded 784 -> 800 (25 * 32)
#define LDK 40                // A LDS row length in bf16 (32 + 8 pad)
#define ABS (256 * LDK)       // one A buffer (shorts)
#define BBS (256 * 32)        // one B buffer (shorts), linear for gl_lds
#define BBSB 16384            // one B buffer (bytes)

#define WAITV0 asm volatile("s_waitcnt vmcnt(0)" ::: "memory")
#define WAITL  asm volatile("s_waitcnt lgkmcnt(0)" ::: "memory")
#define SBAR   __builtin_amdgcn_s_barrier()

// ---------------- init: LDS-tiled transpose (coalesced both sides) ----------------
__global__ __launch_bounds__(256) void init_kernel(
    const float* __restrict__ W1, const float* __restrict__ W2,
    const float* __restrict__ Wp, const float* __restrict__ bp,
    const float* __restrict__ Wr1, const float* __restrict__ br1,
    const float* __restrict__ Wr2, const float* __restrict__ br2,
    short* __restrict__ w1t, short* __restrict__ w2t,
    float* __restrict__ ptabs)
{
    const int b = blockIdx.x;
    if (b < 200) {
        const int kt = b >> 3, nt = b & 7;
        __shared__ float tile[32][33];
        const int x = threadIdx.x & 31, y = threadIdx.x >> 5;
        #pragma unroll
        for (int r = 0; r < 4; ++r) {
            int kl = y + r * 8;
            int k = kt * 32 + kl, n = nt * 32 + x;
            tile[kl][x] = (k < 784) ? W1[k * 256 + n] : 0.f;
        }
        __syncthreads();
        #pragma unroll
        for (int r = 0; r < 4; ++r) {
            int nl = y + r * 8;
            int n = nt * 32 + nl, k = kt * 32 + x;
            w1t[n * KP + k] = f2bf(tile[x][nl]);
        }
    } else {
        for (int i = threadIdx.x; i < 16 * 256; i += 256) {
            int n = i >> 8, k = i & 255;
            float v = (n < 10) ? W2[k * 10 + n] : 0.f;
            w2t[i] = f2bf(v);
        }
        if (threadIdx.x < 8) {
            int which = threadIdx.x >> 2, p = threadIdx.x & 3;
            const float* Wr = which ? Wr2 : Wr1;
            const float* br = which ? br2 : br1;
            float s[4];
            for (int q = 0; q < 4; q++) {
                float a = br[q];
                for (int j = 0; j < 16; j++) a += (Wp[p * 16 + j] + bp[j]) * Wr[j * 4 + q];
                s[q] = a;
            }
            float m = fmaxf(fmaxf(s[0], s[1]), fmaxf(s[2], s[3]));
            float e[4]; float tot = 0.f;
            for (int q = 0; q < 4; q++) { e[q] = __expf(s[q] - m); tot += e[q]; }
            for (int q = 0; q < 4; q++) ptabs[which * 16 + p * 4 + q] = e[q] / tot;
        }
    }
}

// ---------------- fused main kernel ----------------
// 256 blocks x 1024 threads (16 waves, 4x4 wave grid). Tile 256 rows x 256 cols,
// BK=32, R2 cadence (one barrier/step). Full occupancy: 2 blocks/CU = 32 waves/CU.
// A reg-staged fp32->bf16 into [2][256][40]; B via global_load_lds [2][256][32]
// linear with 16-B-slot XOR source-pre-swizzle (R8-proven).
__global__ __launch_bounds__(1024, 8) void fused_kernel(
    const float* __restrict__ g_in, const float* __restrict__ onehot,
    const float* __restrict__ b1g, const float* __restrict__ b2g,
    const short* __restrict__ w1t, const short* __restrict__ w2t,
    const float* __restrict__ ptabs, float* __restrict__ out)
{
    __shared__ __align__(16) char lds[78336];
    short* Abuf = (short*)lds;                  // [2][256][40] bf16 = 40,960 B
    short* Bbuf = (short*)(lds + 40960);        // [2][256][32] bf16 = 32,768 B (ends 73,728)
    short* h1   = (short*)lds;                  // overlay: [128][264] bf16 = 67,584 B
    float* probs = (float*)(lds + 67584);       // [128][16] f32 = 8,192 B (ends 75,776)
    float* dist1 = (float*)(lds + 75776);       // [32][10] f32 = 1,280 B
    float* dist2 = (float*)(lds + 77056);       // [32][10] f32 = 1,280 B (ends 78,336)

    const int t = threadIdx.x;
    const int lane = t & 63, wave = t >> 6;     // wave 0..15
    const int l16 = lane & 15, lg = lane >> 4;
    const int wr = wave >> 2, wc = wave & 3;    // 4x4 wave grid
    const int blk = blockIdx.x;

    // A staging: thread -> (row ar 0..255, 8-float chunk aq 0..3)
    const int ar = t >> 2, aq = t & 3;
    const float* gA = g_in + ((long)blk * 256 + ar) * 784 + aq * 8;
    short* awp = Abuf + ar * LDK + aq * 8;
    // B staging via gl_lds: thread -> (w1t row t>>2, 16-B slot t&3), source XOR-swizzled
    const int brow = t >> 2, bslot = t & 3;
    const short* gBsw = w1t + brow * KP + ((bslot ^ (brow & 3)) * 8);
    char* ldsB = (char*)Bbuf;
    const int bswz = lg ^ (l16 & 3);            // frag-read slot swizzle (matches source)

    f32x4 acc[4][4];
    #pragma unroll
    for (int mi = 0; mi < 4; mi++)
        #pragma unroll
        for (int ni = 0; ni < 4; ni++)
            acc[mi][ni] = (f32x4)0.f;

    f32x4 x0, x1;

    auto issueB = [&](int kt) {                 // B tile kt -> buf kt&1 (1 gl_lds/thread)
        gl2lds16(gBsw + kt * 32, ldsB + (kt & 1) * BBSB + t * 16);
    };
    auto loadA = [&](int kt) {
        const int k0 = kt * 32;
        if (k0 + aq * 8 < 784) {                // 8-aligned chunks: fully valid or fully pad
            x0 = *(const f32x4*)(gA + k0);
            x1 = *(const f32x4*)(gA + k0 + 4);
        } else { x0 = (f32x4)0.f; x1 = (f32x4)0.f; }
    };
    auto writeA = [&](int kt) {
        bf16x8 a8;
        a8[0] = f2bf(x0[0]); a8[1] = f2bf(x0[1]); a8[2] = f2bf(x0[2]); a8[3] = f2bf(x0[3]);
        a8[4] = f2bf(x1[0]); a8[5] = f2bf(x1[1]); a8[6] = f2bf(x1[2]); a8[7] = f2bf(x1[3]);
        *(bf16x8*)(awp + (kt & 1) * ABS) = a8;
    };
    auto mfmaStep = [&](int buf) {
        const short* ab = Abuf + buf * ABS;
        const short* bb = Bbuf + buf * BBS;
        bf16x8 aF[4], bF[4];
        #pragma unroll
        for (int mi = 0; mi < 4; mi++)
            aF[mi] = *(const bf16x8*)(ab + (wr * 64 + mi * 16 + l16) * LDK + lg * 8);
        #pragma unroll
        for (int ni = 0; ni < 4; ni++)
            bF[ni] = *(const bf16x8*)(bb + (wc * 64 + ni * 16 + l16) * 32 + bswz * 8);
        #pragma unroll
        for (int mi = 0; mi < 4; mi++)
            #pragma unroll
            for (int ni = 0; ni < 4; ni++)
                acc[mi][ni] = __builtin_amdgcn_mfma_f32_16x16x32_bf16(aF[mi], bF[ni], acc[mi][ni], 0, 0, 0);
    };

    // ---- prologue: B(0), A(0) -> buf0, publish ----
    issueB(0);
    loadA(0);
    writeA(0);
    WAITV0; WAITL; SBAR;

    // ---- K-loop: 25 steps, one barrier per step (R2 cadence) ----
    for (int kt = 0; kt < 25; ++kt) {
        const bool more = (kt < 24);
        if (more) { issueB(kt + 1); loadA(kt + 1); }
        mfmaStep(kt & 1);
        if (more) writeA(kt + 1);               // auto vmcnt wait drains A loads
        WAITV0;                                  // drain gl_lds (B) before publish
        WAITL; SBAR;
    }

    // ---- epilogue in two 128-row halves (h1 overlays staging buffers) ----
    const float b2v = (l16 < 10) ? b2g[l16] : 0.f;
    for (int h = 0; h < 2; ++h) {
        if ((wave >> 3) == h) {                 // waves owning this half write h1
            #pragma unroll
            for (int mi = 0; mi < 4; mi++) {
                const int R = (wr & 1) * 64 + mi * 16 + lg * 4;
                #pragma unroll
                for (int ni = 0; ni < 4; ni++) {
                    const int N = wc * 64 + ni * 16 + l16;
                    const float bias = b1g[N];
                    #pragma unroll
                    for (int j = 0; j < 4; j++)
                        h1[(R + j) * 264 + N] = f2bf(fmaxf(acc[mi][ni][j] + bias, 0.f));
                }
            }
        }
        __syncthreads();

        // GEMM2 + softmax: waves 0-7, 16 rows each
        if (wave < 8) {
            f32x4 acc2 = (f32x4)0.f;
            const short* h1r = h1 + (wave * 16 + l16) * 264 + lg * 8;
            const short* w2r = w2t + l16 * 256 + lg * 8;
            #pragma unroll
            for (int kk = 0; kk < 8; kk++) {
                bf16x8 a2 = *(const bf16x8*)(h1r + kk * 32);
                bf16x8 b2f = *(const bf16x8*)(w2r + kk * 32);
                acc2 = __builtin_amdgcn_mfma_f32_16x16x32_bf16(a2, b2f, acc2, 0, 0, 0);
            }
            float pv[4], mx[4];
            #pragma unroll
            for (int j = 0; j < 4; j++) {
                pv[j] = (l16 < 10) ? (acc2[j] + b2v) * 10.f : -1e30f;
                mx[j] = pv[j];
            }
            #pragma unroll
            for (int off = 1; off < 16; off <<= 1)
                #pragma unroll
                for (int j = 0; j < 4; j++)
                    mx[j] = fmaxf(mx[j], __shfl_xor(mx[j], off));
            float ex[4], sm[4];
            #pragma unroll
            for (int j = 0; j < 4; j++) { ex[j] = __expf(pv[j] - mx[j]); sm[j] = ex[j]; }
            #pragma unroll
            for (int off = 1; off < 16; off <<= 1)
                #pragma unroll
                for (int j = 0; j < 4; j++)
                    sm[j] += __shfl_xor(sm[j], off);
            #pragma unroll
            for (int j = 0; j < 4; j++)
                probs[(wave * 16 + lg * 4 + j) * 16 + l16] = ex[j] / sm[j];
        }
        __syncthreads();

        // pointer mix: 32 samples x 10 digits
        if (t < 320) {
            int s = t / 10, d = t - s * 10;
            const float* oh = onehot + ((long)blk * 64 + h * 32 + s) * 4;
            int pid = (int)(oh[1] + 2.f * oh[2] + 3.f * oh[3] + 0.5f);
            const float* p1t = ptabs + pid * 4;
            const float* p2t = ptabs + 16 + pid * 4;
            float d1 = 0.f, d2 = 0.f;
            #pragma unroll
            for (int p = 0; p < 4; p++) {
                float pr = probs[(s * 4 + p) * 16 + d];
                d1 += p1t[p] * pr;
                d2 += p2t[p] * pr;
            }
            dist1[s * 10 + d] = d1;
            dist2[s * 10 + d] = d2;
        }
        __syncthreads();

        // conv (i+j==k symmetric: symmetrization is a no-op) + log
        if (t < 608) {
            int s = t / 19, k = t - s * 19;
            int ilo = k > 9 ? k - 9 : 0;
            int ihi = k < 9 ? k : 9;
            float sum = 0.f;
            for (int i = ilo; i <= ihi; i++)
                sum += dist1[s * 10 + i] * dist2[s * 10 + (k - i)];
            out[((long)blk * 64 + h * 32 + s) * 19 + k] = __logf(sum + 1e-10f);
        }
        __syncthreads();                        // protect h1/probs/dist before next half
    }
}

extern "C" void kernel_launch(void* const* d_in, const int* in_sizes, int n_in,
                              void* d_out, int out_size, void* d_ws, size_t ws_size,
                              hipStream_t stream)
{
    const float* grid   = (const float*)d_in[0];
    const float* onehot = (const float*)d_in[1];
    const float* W1  = (const float*)d_in[2];
    const float* b1  = (const float*)d_in[3];
    const float* W2  = (const float*)d_in[4];
    const float* b2  = (const float*)d_in[5];
    const float* Wp  = (const float*)d_in[6];
    const float* bp  = (const float*)d_in[7];
    const float* Wr1 = (const float*)d_in[8];
    const float* br1 = (const float*)d_in[9];
    const float* Wr2 = (const float*)d_in[10];
    const float* br2 = (const float*)d_in[11];
    float* out = (float*)d_out;

    short* w1t = (short*)d_ws;              // 256 x 800 bf16 = 409,600 B
    short* w2t = w1t + 256 * KP;            // 16 x 256 bf16  = 8,192 B
    float* ptabs = (float*)(w2t + 16 * 256);// 2 x 4 x 4 f32  = 128 B

    init_kernel<<<201, 256, 0, stream>>>(W1, W2, Wp, bp, Wr1, br1, Wr2, br2, w1t, w2t, ptabs);

    const int B = in_sizes[1] / 4;          // 16384
    const int nblk = (B * 4) / 256;         // 256 blocks
    fused_kernel<<<nblk, 1024, 0, stream>>>(grid, onehot, b1, b2, w1t, w2t, ptabs, out);
}

// Round 10
// 72.342 us; speedup vs baseline: 5.7343x; 5.7343x over previous
//
#include <hip/hip_runtime.h>
#include <hip/hip_bf16.h>

typedef __attribute__((ext_vector_type(8))) short bf16x8;
typedef __attribute__((ext_vector_type(4))) short s16x4;
typedef __attribute__((ext_vector_type(4))) float f32x4;

__device__ __forceinline__ short f2bf(float f) {
    union { float f; unsigned u; } v; v.f = f;
    unsigned r = v.u + 0x7fffu + ((v.u >> 16) & 1u);
    return (short)(r >> 16);
}

__device__ __forceinline__ void gl2lds16(const void* g, void* l) {
    __builtin_amdgcn_global_load_lds(
        (const __attribute__((address_space(1))) unsigned int*)g,
        (__attribute__((address_space(3))) unsigned int*)l,
        16, 0, 0);
}

#define KP  800               // K padded 784 -> 800 (25 * 32)
#define LDK 40                // A LDS row length in bf16 (32 + 8 pad)
#define ABS (64 * LDK)        // one A buffer (shorts)
#define BBS (256 * 32)        // one B buffer (shorts), linear for gl_lds
#define BBSB 16384            // one B buffer (bytes)

#define WAITV0 asm volatile("s_waitcnt vmcnt(0)" ::: "memory")
#define WAITL  asm volatile("s_waitcnt lgkmcnt(0)" ::: "memory")
#define SBAR   __builtin_amdgcn_s_barrier()

// ---------------- init: LDS-tiled transpose (coalesced both sides) ----------------
__global__ __launch_bounds__(256) void init_kernel(
    const float* __restrict__ W1, const float* __restrict__ W2,
    const float* __restrict__ Wp, const float* __restrict__ bp,
    const float* __restrict__ Wr1, const float* __restrict__ br1,
    const float* __restrict__ Wr2, const float* __restrict__ br2,
    short* __restrict__ w1t, short* __restrict__ w2t,
    float* __restrict__ ptabs)
{
    const int b = blockIdx.x;
    if (b < 200) {
        const int kt = b >> 3, nt = b & 7;
        __shared__ float tile[32][33];
        const int x = threadIdx.x & 31, y = threadIdx.x >> 5;
        #pragma unroll
        for (int r = 0; r < 4; ++r) {
            int kl = y + r * 8;
            int k = kt * 32 + kl, n = nt * 32 + x;
            tile[kl][x] = (k < 784) ? W1[k * 256 + n] : 0.f;
        }
        __syncthreads();
        #pragma unroll
        for (int r = 0; r < 4; ++r) {
            int nl = y + r * 8;
            int n = nt * 32 + nl, k = kt * 32 + x;
            w1t[n * KP + k] = f2bf(tile[x][nl]);
        }
    } else {
        for (int i = threadIdx.x; i < 16 * 256; i += 256) {
            int n = i >> 8, k = i & 255;
            float v = (n < 10) ? W2[k * 10 + n] : 0.f;
            w2t[i] = f2bf(v);
        }
        if (threadIdx.x < 8) {
            int which = threadIdx.x >> 2, p = threadIdx.x & 3;
            const float* Wr = which ? Wr2 : Wr1;
            const float* br = which ? br2 : br1;
            float s[4];
            for (int q = 0; q < 4; q++) {
                float a = br[q];
                for (int j = 0; j < 16; j++) a += (Wp[p * 16 + j] + bp[j]) * Wr[j * 4 + q];
                s[q] = a;
            }
            float m = fmaxf(fmaxf(s[0], s[1]), fmaxf(s[2], s[3]));
            float e[4]; float tot = 0.f;
            for (int q = 0; q < 4; q++) { e[q] = __expf(s[q] - m); tot += e[q]; }
            for (int q = 0; q < 4; q++) ptabs[which * 16 + p * 4 + q] = e[q] / tot;
        }
    }
}

// ---------------- fused main kernel ----------------
// 1024 blocks x 512 threads (8 waves). Tile 64 rows x 256 cols, BK=32, R2 cadence.
// Per-wave output 32x64 -> acc[2][4] (32 VGPR) so launch_bounds(512,6) fits WITHOUT
// spilling: 3 blocks/CU = 24 waves/CU (6/SIMD), +50% occupancy vs R2.
// A reg-staged fp32->bf16 [2][64][40]; B via global_load_lds [2][256][32] linear
// with 16-B-slot XOR source-pre-swizzle (R8-proven correct).
__global__ __launch_bounds__(512, 6) void fused_kernel(
    const float* __restrict__ g_in, const float* __restrict__ onehot,
    const float* __restrict__ b1g, const float* __restrict__ b2g,
    const short* __restrict__ w1t, const short* __restrict__ w2t,
    const float* __restrict__ ptabs, float* __restrict__ out)
{
    __shared__ __align__(16) char lds[43008];
    short* Abuf = (short*)lds;                  // [2][64][40] bf16 = 10,240 B
    short* Bbuf = (short*)(lds + 10240);        // [2][256][32] bf16 = 32,768 B (ends 43,008)
    short* h1   = (short*)lds;                  // overlay: [64][264] bf16 = 33,792 B
    float* probs = (float*)(lds + 33792);       // [64][16] f32 = 4,096 B (ends 37,888)
    float* dist1 = (float*)(lds + 37888);       // [16][10] f32 = 640 B
    float* dist2 = (float*)(lds + 38528);       // [16][10] f32 = 640 B (ends 39,168)

    const int t = threadIdx.x;
    const int lane = t & 63, wave = t >> 6;
    const int l16 = lane & 15, lg = lane >> 4;
    const int wr = wave >> 2, wc = wave & 3;    // 2x4 wave grid, 32x64 output each
    const int blk = blockIdx.x;

    // A staging: thread -> (row t>>3 of 64, 4-float chunk q = t&7)
    const int arow = t >> 3, aq = t & 7;
    const float* gA = g_in + ((long)blk * 64 + arow) * 784 + aq * 4;
    short* awp = Abuf + arow * LDK + aq * 4;
    // B staging via gl_lds: thread covers w1t rows t>>2 and (t>>2)+128, slot t&3,
    // source chunk XOR-swizzled by (row&3); frag read uses matching slot swizzle.
    const int brow = t >> 2, bslot = t & 3;
    const short* gBsw = w1t + brow * KP + ((bslot ^ (brow & 3)) * 8);
    char* ldsB = (char*)Bbuf;
    const int bswz = lg ^ (l16 & 3);

    f32x4 acc[2][4];
    #pragma unroll
    for (int mi = 0; mi < 2; mi++)
        #pragma unroll
        for (int ni = 0; ni < 4; ni++)
            acc[mi][ni] = (f32x4)0.f;

    f32x4 x0;

    auto issueB = [&](int kt) {                 // B tile kt -> buf kt&1 (2 gl_lds/thread)
        const short* g0 = gBsw + kt * 32;
        char* l0 = ldsB + (kt & 1) * BBSB + wave * 1024;
        gl2lds16(g0, l0);
        gl2lds16(g0 + 128 * KP, l0 + 8192);
    };
    auto loadA = [&](int kt) {
        const int k0 = kt * 32;
        if (k0 + aq * 4 < 784) x0 = *(const f32x4*)(gA + k0);
        else x0 = (f32x4)0.f;
    };
    auto writeA = [&](int kt) {
        s16x4 a4;
        a4[0] = f2bf(x0[0]); a4[1] = f2bf(x0[1]); a4[2] = f2bf(x0[2]); a4[3] = f2bf(x0[3]);
        *(s16x4*)(awp + (kt & 1) * ABS) = a4;
    };
    auto mfmaStep = [&](int buf) {
        const short* ab = Abuf + buf * ABS;
        const short* bb = Bbuf + buf * BBS;
        bf16x8 aF[2], bF[4];
        #pragma unroll
        for (int mi = 0; mi < 2; mi++)
            aF[mi] = *(const bf16x8*)(ab + (wr * 32 + mi * 16 + l16) * LDK + lg * 8);
        #pragma unroll
        for (int ni = 0; ni < 4; ni++)
            bF[ni] = *(const bf16x8*)(bb + (wc * 64 + ni * 16 + l16) * 32 + bswz * 8);
        #pragma unroll
        for (int mi = 0; mi < 2; mi++)
            #pragma unroll
            for (int ni = 0; ni < 4; ni++)
                acc[mi][ni] = __builtin_amdgcn_mfma_f32_16x16x32_bf16(aF[mi], bF[ni], acc[mi][ni], 0, 0, 0);
    };

    // ---- prologue ----
    issueB(0);
    loadA(0);
    writeA(0);
    WAITV0; WAITL; SBAR;

    // ---- K-loop: 25 steps, one barrier per step (R2 cadence) ----
    for (int kt = 0; kt < 25; ++kt) {
        const bool more = (kt < 24);
        if (more) { issueB(kt + 1); loadA(kt + 1); }
        mfmaStep(kt & 1);
        if (more) writeA(kt + 1);               // auto vmcnt wait covers A (and B) arrival
        WAITV0;                                  // drain gl_lds before publishing
        WAITL; SBAR;
    }

    // ---- epilogue 1: h1 = relu(acc + b1) (overlay; 64 rows) ----
    #pragma unroll
    for (int mi = 0; mi < 2; mi++) {
        const int R = wr * 32 + mi * 16 + lg * 4;
        #pragma unroll
        for (int ni = 0; ni < 4; ni++) {
            const int N = wc * 64 + ni * 16 + l16;
            const float bias = b1g[N];
            #pragma unroll
            for (int j = 0; j < 4; j++)
                h1[(R + j) * 264 + N] = f2bf(fmaxf(acc[mi][ni][j] + bias, 0.f));
        }
    }
    __syncthreads();

    // ---- GEMM2 (waves 0-3): logits = h1 @ W2 (+b2), 16 rows/wave ----
    if (wave < 4) {
        f32x4 acc2 = (f32x4)0.f;
        const short* h1r = h1 + (wave * 16 + l16) * 264 + lg * 8;
        const short* w2r = w2t + l16 * 256 + lg * 8;
        #pragma unroll
        for (int kk = 0; kk < 8; kk++) {
            bf16x8 a2 = *(const bf16x8*)(h1r + kk * 32);
            bf16x8 b2f = *(const bf16x8*)(w2r + kk * 32);
            acc2 = __builtin_amdgcn_mfma_f32_16x16x32_bf16(a2, b2f, acc2, 0, 0, 0);
        }
        // softmax(logits/0.1): C frag row = lg*4+j, col = l16
        const float b2v = (l16 < 10) ? b2g[l16] : 0.f;
        float pv[4], mx[4];
        #pragma unroll
        for (int j = 0; j < 4; j++) {
            pv[j] = (l16 < 10) ? (acc2[j] + b2v) * 10.f : -1e30f;
            mx[j] = pv[j];
        }
        #pragma unroll
        for (int off = 1; off < 16; off <<= 1)
            #pragma unroll
            for (int j = 0; j < 4; j++)
                mx[j] = fmaxf(mx[j], __shfl_xor(mx[j], off));
        float ex[4], sm[4];
        #pragma unroll
        for (int j = 0; j < 4; j++) { ex[j] = __expf(pv[j] - mx[j]); sm[j] = ex[j]; }
        #pragma unroll
        for (int off = 1; off < 16; off <<= 1)
            #pragma unroll
            for (int j = 0; j < 4; j++)
                sm[j] += __shfl_xor(sm[j], off);
        #pragma unroll
        for (int j = 0; j < 4; j++)
            probs[(wave * 16 + lg * 4 + j) * 16 + l16] = ex[j] / sm[j];
    }
    __syncthreads();

    // ---- pointer mix: 16 samples x 10 digits ----
    if (t < 160) {
        int s = t / 10, d = t - s * 10;
        const float* oh = onehot + ((long)blk * 16 + s) * 4;
        int pid = (int)(oh[1] + 2.f * oh[2] + 3.f * oh[3] + 0.5f);
        const float* p1t = ptabs + pid * 4;
        const float* p2t = ptabs + 16 + pid * 4;
        float d1 = 0.f, d2 = 0.f;
        #pragma unroll
        for (int p = 0; p < 4; p++) {
            float pr = probs[(s * 4 + p) * 16 + d];
            d1 += p1t[p] * pr;
            d2 += p2t[p] * pr;
        }
        dist1[s * 10 + d] = d1;
        dist2[s * 10 + d] = d2;
    }
    __syncthreads();

    // ---- conv (i+j==k symmetric: symmetrization is a no-op) + log ----
    if (t < 304) {
        int s = t / 19, k = t - s * 19;
        int ilo = k > 9 ? k - 9 : 0;
        int ihi = k < 9 ? k : 9;
        float sum = 0.f;
        for (int i = ilo; i <= ihi; i++)
            sum += dist1[s * 10 + i] * dist2[s * 10 + (k - i)];
        out[((long)blk * 16 + s) * 19 + k] = __logf(sum + 1e-10f);
    }
}

extern "C" void kernel_launch(void* const* d_in, const int* in_sizes, int n_in,
                              void* d_out, int out_size, void* d_ws, size_t ws_size,
                              hipStream_t stream)
{
    const float* grid   = (const float*)d_in[0];
    const float* onehot = (const float*)d_in[1];
    const float* W1  = (const float*)d_in[2];
    const float* b1  = (const float*)d_in[3];
    const float* W2  = (const float*)d_in[4];
    const float* b2  = (const float*)d_in[5];
    const float* Wp  = (const float*)d_in[6];
    const float* bp  = (const float*)d_in[7];
    const float* Wr1 = (const float*)d_in[8];
    const float* br1 = (const float*)d_in[9];
    const float* Wr2 = (const float*)d_in[10];
    const float* br2 = (const float*)d_in[11];
    float* out = (float*)d_out;

    short* w1t = (short*)d_ws;              // 256 x 800 bf16 = 409,600 B
    short* w2t = w1t + 256 * KP;            // 16 x 256 bf16  = 8,192 B
    float* ptabs = (float*)(w2t + 16 * 256);// 2 x 4 x 4 f32  = 128 B

    init_kernel<<<201, 256, 0, stream>>>(W1, W2, Wp, bp, Wr1, br1, Wr2, br2, w1t, w2t, ptabs);

    const int B = in_sizes[1] / 4;          // 16384
    const int nblk = (B * 4) / 64;          // 1024 blocks
    fused_kernel<<<nblk, 512, 0, stream>>>(grid, onehot, b1, b2, w1t, w2t, ptabs, out);
}